// Round 3
// baseline (2058.833 us; speedup 1.0000x reference)
//
#include <hip/hip_runtime.h>
#include <math.h>

#define NWAY 5
#define NSUP 25
#define NZV  125
#define DF   640
#define NQ   75
#define TPB  320

// ---------------- shared-memory offsets for qp_kernel (in doubles) ----------
#define OFF_HINV 0      // 5 * 25*26 = 3250
#define OFF_WINV 3250   // 650
#define OFF_X    3900
#define OFF_S    4028
#define OFF_Z    4156
#define OFF_BX   4284
#define OFF_RX   4412
#define OFF_RZ   4540
#define OFF_TT   4668
#define OFF_C1   4796
#define OFF_DD   4924
#define OFF_VV   5052
#define OFF_DXA  5180
#define OFF_DSA  5308
#define OFF_DZA  5436
#define OFF_RSC  5564
#define OFF_DXC  5692
#define OFF_DSC  5820
#define OFF_DZC  5948
#define OFF_YV   6076   // 32 each from here
#define OFF_RY   6108
#define OFF_C2   6140
#define OFF_GG   6172
#define OFF_DYA  6204
#define OFF_DYC  6236
#define OFF_Z125 6268   // 128 zeros
#define OFF_Z25  6396   // 32 zeros
#define OFF_SC   6428   // scalars: [0]=best_res [1]=better flag [15]=reduce slot
#define SH_TOT   6448

__device__ __forceinline__ float simple_tf(float x) {
  float tp = fmaxf(x, 0.0f) + 1e-5f;
  float tn = fmaxf(-x, 0.0f) + 1e-5f;
  float lp = __logf(1.0f / tp + 1.0f);
  float ln_ = __logf(1.0f / tn + 1.0f);
  float pos = __expf(-1.3f * __logf(lp));
  float neg = __expf(-1.3f * __logf(ln_));
  return pos - neg;
}

// =====================================================================
// Kernel 1: transform + l2norm train features, Gram K, M = K + I (fp64)
// =====================================================================
__global__ void __launch_bounds__(TPB, 2) feat_kernel(
    const float* __restrict__ train, const int* __restrict__ usimple,
    double* __restrict__ Mg) {
  const int b = blockIdx.x;
  const int tid = threadIdx.x;
  const int lane = tid & 63;
  const int w = tid >> 6;
  __shared__ __align__(16) float ftn[NSUP * 644];   // padded stride 644
  const bool us = (usimple[0] != 0);
  const float* tb = train + (size_t)b * NSUP * DF;

  for (int idx = tid; idx < NSUP * DF; idx += TPB) {
    float v = tb[idx];
    if (us) v = simple_tf(v);
    int r = idx / DF, c = idx - r * DF;
    ftn[r * 644 + c] = v;
  }
  __syncthreads();
#pragma unroll
  for (int jj = 0; jj < 5; ++jj) {
    const int r = w + 5 * jj;
    float acc = 0.0f;
#pragma unroll
    for (int c = 0; c < 10; ++c) {
      float t = ftn[r * 644 + lane + 64 * c];
      acc += t * t;
    }
#pragma unroll
    for (int off = 32; off > 0; off >>= 1) acc += __shfl_xor(acc, off);
    const float sc = 1.0f / fmaxf(sqrtf(acc), 1e-12f);
#pragma unroll
    for (int c = 0; c < 10; ++c) ftn[r * 644 + lane + 64 * c] *= sc;
  }
  __syncthreads();
  double* Mb = Mg + (size_t)b * 650;
  for (int pi = tid; pi < 325; pi += TPB) {
    int i = 0, rem = pi;
    while (rem >= NSUP - i) { rem -= NSUP - i; ++i; }
    const int j = i + rem;
    const float4* ra = (const float4*)(ftn + i * 644);
    const float4* rb = (const float4*)(ftn + j * 644);
    double acc = 0.0;
    for (int c = 0; c < 160; ++c) {
      float4 av = ra[c], bv = rb[c];
      acc += (double)av.x * bv.x + (double)av.y * bv.y +
             (double)av.z * bv.z + (double)av.w * bv.w;
    }
    if (i == j) acc += 1.0;
    Mb[i * 26 + j] = acc;
    if (i != j) Mb[j * 26 + i] = acc;
  }
}

// =====================================================================
// Template-unrolled 25x25 register Cholesky + inverse column solve.
// All indices compile-time; EVERYTHING on the factorization path is
// force-inlined into the kernel: noinline callees get the DEFAULT
// register budget (~128 VGPR) regardless of kernel launch_bounds, which
// is what spilled the two fp64[25] arrays to scratch in R1/R2 (2 GB of
// private traffic = the whole runtime).
// =====================================================================
template <int J, int P>
__device__ __forceinline__ void chol_inner(double (&a)[25], const int lane) {
  if constexpr (P < 25) {
    const double apj = __shfl(a[J], P);
    if (lane > J) a[P] -= a[J] * apj;
    chol_inner<J, P + 1>(a, lane);
  }
}
template <int J>
__device__ __forceinline__ void chol_outer(double (&a)[25], const int lane) {
  if constexpr (J < 25) {
    const double djj = __shfl(a[J], J);
    const double rL = 1.0 / sqrt(djj);
    if (lane == J) a[J] = rL;
    else if (lane > J) a[J] *= rL;
    chol_inner<J, J + 1>(a, lane);
    chol_outer<J + 1>(a, lane);
  }
}
template <int I, int P>
__device__ __forceinline__ void fwd_dot(const double (&a)[25],
                                        const double (&col)[25], double& t) {
  if constexpr (P < I) {
    t -= __shfl(a[P], I) * col[P];
    fwd_dot<I, P + 1>(a, col, t);
  }
}
template <int I>
__device__ __forceinline__ void fwd_solve(const double (&a)[25],
                                          double (&col)[25], const int lane) {
  if constexpr (I < 25) {
    double t = (lane == I) ? 1.0 : 0.0;
    fwd_dot<I, 0>(a, col, t);
    col[I] = t * __shfl(a[I], I);
    fwd_solve<I + 1>(a, col, lane);
  }
}
template <int I, int P>
__device__ __forceinline__ void bwd_dot(const double (&a)[25],
                                        const double (&col)[25], double& t) {
  if constexpr (P < 25) {
    t -= __shfl(a[I], P) * col[P];
    bwd_dot<I, P + 1>(a, col, t);
  }
}
template <int I>
__device__ __forceinline__ void bwd_solve(const double (&a)[25],
                                          double (&col)[25]) {
  if constexpr (I >= 0) {
    double t = col[I];
    bwd_dot<I, I + 1>(a, col, t);
    col[I] = t * __shfl(a[I], I);
    bwd_solve<I - 1>(a, col);
  }
}
__device__ __forceinline__ void cholinv25(double (&a)[25], double (&col)[25],
                                          const int lane) {
  chol_outer<0>(a, lane);      // in-place L (diag holds 1/L[j][j])
  fwd_solve<0>(a, col, lane);  // L y = e_lane
  bwd_solve<24>(a, col);       // L^T x = y  -> col = Hinv column `lane`
}

__device__ __forceinline__ void factorize(const double* Msh, double* SH,
                                          const int tid) {
  const int lane = tid & 63;
  const int w = tid >> 6;
  const double* dd = SH + OFF_DD;
  double* Hinv = SH + OFF_HINV;
  double* Winv = SH + OFF_WINV;
  {
    double a[25], col[25];
#pragma unroll
    for (int j = 0; j < 25; ++j) a[j] = 0.0;
    if (lane < 25) {
#pragma unroll
      for (int j = 0; j < 25; ++j)
        a[j] = Msh[lane * 26 + j] + ((j == lane) ? dd[lane * 5 + w] : 0.0);
    }
    cholinv25(a, col, lane);
    if (lane < 25) {
#pragma unroll
      for (int i = 0; i < 25; ++i) Hinv[w * 650 + i * 26 + lane] = col[i];
    }
  }
  __syncthreads();
  for (int idx = tid; idx < 625; idx += TPB) {
    const int i = idx / 25, r = idx - i * 25;
    double acc = 0.0;
#pragma unroll
    for (int k = 0; k < 5; ++k) acc += Hinv[k * 650 + i * 26 + r];
    Winv[i * 26 + r] = acc;
  }
  __syncthreads();
  if (w == 0) {
    double a[25], col[25];
#pragma unroll
    for (int j = 0; j < 25; ++j) a[j] = 0.0;
    if (lane < 25) {
#pragma unroll
      for (int j = 0; j < 25; ++j) a[j] = Winv[lane * 26 + j];
    }
    cholinv25(a, col, lane);
    if (lane < 25) {
#pragma unroll
      for (int i = 0; i < 25; ++i) Winv[i * 26 + lane] = col[i];
    }
  }
  __syncthreads();
}

__device__ __forceinline__ void kkt_solve(
    const double* Msh, double* SH, const double* rx, const double* rs,
    const double* rz, const double* ry, double* dx, double* ds, double* dz,
    double* dy, const int tid) {
  const int lane = tid & 63;
  const int w = tid >> 6;
  const double* dd = SH + OFF_DD;
  const double* Hinv = SH + OFF_HINV;
  const double* Winv = SH + OFF_WINV;
  double* tt = SH + OFF_TT;
  double* c1 = SH + OFF_C1;
  double* c2 = SH + OFF_C2;
  double* vv = SH + OFF_VV;
  double* gg = SH + OFF_GG;

  if (tid < NZV) tt[tid] = rz[tid] - rs[tid] / dd[tid];
  __syncthreads();
  if (tid < NZV) {
    const int i = tid / 5, k = tid - i * 5;
    double acc = -rx[tid];
#pragma unroll
    for (int j = 0; j < 25; ++j) acc += Msh[i * 26 + j] * tt[j * 5 + k];
    c1[tid] = acc;
  } else if (tid >= 128 && tid < 153) {
    const int i = tid - 128;
    double acc = -ry[i];
#pragma unroll
    for (int k = 0; k < 5; ++k) acc += tt[i * 5 + k];
    c2[i] = acc;
  }
  __syncthreads();
  if (lane < 25) {
    double acc = 0.0;
#pragma unroll
    for (int j = 0; j < 25; ++j)
      acc += Hinv[w * 650 + lane * 26 + j] * c1[j * 5 + w];
    vv[lane * 5 + w] = acc;
  }
  __syncthreads();
  if (tid < 25) {
    double acc = -c2[tid];
#pragma unroll
    for (int k = 0; k < 5; ++k) acc += vv[tid * 5 + k];
    gg[tid] = acc;
  }
  __syncthreads();
  if (tid < 25) {
    double acc = 0.0;
#pragma unroll
    for (int r = 0; r < 25; ++r) acc += Winv[tid * 26 + r] * gg[r];
    dy[tid] = acc;
  }
  __syncthreads();
  if (lane < 25) {
    double acc = 0.0;
#pragma unroll
    for (int j = 0; j < 25; ++j) acc += Hinv[w * 650 + lane * 26 + j] * dy[j];
    const int v = lane * 5 + w;
    const double u = vv[v] - acc;
    const double dzv = dd[v] * u;
    dz[v] = dzv;
    dx[v] = u - tt[v];
    ds[v] = (-rs[v] - dzv) / dd[v];
  }
  __syncthreads();
}

__device__ __forceinline__ double bred(const double* buf, int n, int ismin,
                                       double* SC, const int tid) {
  __syncthreads();
  if (tid < 64) {
    double acc = ismin ? 1e300 : 0.0;
    for (int m = tid; m < n; m += 64) {
      const double v = buf[m];
      acc = ismin ? fmin(acc, v) : (acc + v);
    }
#pragma unroll
    for (int off = 32; off > 0; off >>= 1) {
      const double o = __shfl_xor(acc, off);
      acc = ismin ? fmin(acc, o) : (acc + o);
    }
    if (tid == 0) SC[15] = acc;
  }
  __syncthreads();
  return SC[15];
}

__global__ void __attribute__((amdgpu_waves_per_eu(1, 2)))
__launch_bounds__(TPB) qp_kernel(const double* __restrict__ Mg,
                                 float* __restrict__ xout) {
  const int b = blockIdx.x;
  const int tid = threadIdx.x;
  __shared__ double SH[SH_TOT];
  __shared__ double Msh[NSUP * 26];

  double* x = SH + OFF_X;
  double* s = SH + OFF_S;
  double* z = SH + OFF_Z;
  double* bx = SH + OFF_BX;
  double* rx = SH + OFF_RX;
  double* rz = SH + OFF_RZ;
  double* tt = SH + OFF_TT;
  double* dd = SH + OFF_DD;
  double* dxa = SH + OFF_DXA;
  double* dsa = SH + OFF_DSA;
  double* dza = SH + OFF_DZA;
  double* rsc = SH + OFF_RSC;
  double* dxc = SH + OFF_DXC;
  double* dsc = SH + OFF_DSC;
  double* dzc = SH + OFF_DZC;
  double* yv = SH + OFF_YV;
  double* ry = SH + OFF_RY;
  double* dya = SH + OFF_DYA;
  double* dyc = SH + OFF_DYC;
  double* z125 = SH + OFF_Z125;
  double* z25 = SH + OFF_Z25;
  double* SC = SH + OFF_SC;

  for (int idx = tid; idx < NSUP * 26; idx += TPB)
    Msh[idx] = Mg[(size_t)b * 650 + idx];

  if (tid < NZV) {
    const int i = tid / 5, k = tid - i * 5;
    const double oh = (k == (i % 5)) ? 1.0 : 0.0;
    rx[tid] = -oh;
    rz[tid] = -0.1 * oh;
    dd[tid] = 1.0;
    rsc[tid] = 0.0;
    z125[tid] = 0.0;
  } else if (tid >= 128 && tid < 153) {
    const int i = tid - 128;
    ry[i] = 0.0;
    z25[i] = 0.0;
  }
  if (tid == 0) SC[0] = 1e300;
  __syncthreads();

  factorize(Msh, SH, tid);
  kkt_solve(Msh, SH, rx, rsc, rz, ry, x, s, z, yv, tid);

  {
    const double ms = bred(s, NZV, 1, SC, tid);
    if (ms < 0.0 && tid < NZV) s[tid] -= (ms - 1.0);
    const double mz = bred(z, NZV, 1, SC, tid);
    if (mz < 0.0 && tid < NZV) z[tid] -= (mz - 1.0);
  }
  if (tid < NZV) bx[tid] = x[tid];

#pragma unroll 1
  for (int it = 0; it < 3; ++it) {
    __syncthreads();
    if (tid < NZV) {
      const int i = tid / 5, k = tid - i * 5;
      double acc = 0.0;
#pragma unroll
      for (int j = 0; j < 25; ++j) acc += Msh[i * 26 + j] * x[j * 5 + k];
      const double oh = (k == (i % 5)) ? 1.0 : 0.0;
      rx[tid] = yv[i] + z[tid] + acc - oh;
      rz[tid] = x[tid] + s[tid] - 0.1 * oh;
      tt[tid] = s[tid] * z[tid];
    } else if (tid >= 128 && tid < 153) {
      const int i = tid - 128;
      double acc = 0.0;
#pragma unroll
      for (int k = 0; k < 5; ++k) acc += x[i * 5 + k];
      ry[i] = acc;
    }
    const double szsum = bred(tt, NZV, 0, SC, tid);
    if (tid < NZV) tt[tid] = rx[tid] * rx[tid];
    const double snx = bred(tt, NZV, 0, SC, tid);
    if (tid < NZV) tt[tid] = rz[tid] * rz[tid];
    const double snz = bred(tt, NZV, 0, SC, tid);
    if (tid < 25) tt[tid] = ry[tid] * ry[tid];
    const double sny = bred(tt, 25, 0, SC, tid);
    const double mu = fabs(szsum) / 125.0;
    const double res = sqrt(snz + 1e-30) + sqrt(sny + 1e-30) +
                       sqrt(snx + 1e-30) + 125.0 * mu;
    if (tid == 0) {
      if (res < SC[0]) { SC[0] = res; SC[1] = 1.0; } else SC[1] = 0.0;
    }
    __syncthreads();
    if (SC[1] != 0.0 && tid < NZV) bx[tid] = x[tid];
    if (it == 2) break;
    __syncthreads();

    if (tid < NZV) dd[tid] = z[tid] / s[tid];
    __syncthreads();
    factorize(Msh, SH, tid);
    kkt_solve(Msh, SH, rx, z, rz, ry, dxa, dsa, dza, dya, tid);
    if (tid < NZV) {
      const double a1 = (dza[tid] < 0.0) ? (-z[tid] / dza[tid]) : 1e12;
      const double a2 = (dsa[tid] < 0.0) ? (-s[tid] / dsa[tid]) : 1e12;
      tt[tid] = fmin(a1, a2);
    }
    const double aff = fmin(bred(tt, NZV, 1, SC, tid), 1.0);
    if (tid < NZV)
      tt[tid] = (s[tid] + aff * dsa[tid]) * (z[tid] + aff * dza[tid]);
    const double num = bred(tt, NZV, 0, SC, tid);
    const double sg = num / szsum;
    const double musig = mu * (sg * sg * sg);
    if (tid < NZV) rsc[tid] = (-musig + dsa[tid] * dza[tid]) / s[tid];
    __syncthreads();
    kkt_solve(Msh, SH, z125, rsc, z125, z25, dxc, dsc, dzc, dyc, tid);
    if (tid < NZV) {
      const double ddx = dxa[tid] + dxc[tid];
      const double dds = dsa[tid] + dsc[tid];
      const double ddz = dza[tid] + dzc[tid];
      dxa[tid] = ddx; dsa[tid] = dds; dza[tid] = ddz;
      const double a1 = (ddz < 0.0) ? (-z[tid] / ddz) : 1e12;
      const double a2 = (dds < 0.0) ? (-s[tid] / dds) : 1e12;
      tt[tid] = fmin(a1, a2);
    } else if (tid >= 128 && tid < 153) {
      const int i = tid - 128;
      dya[i] += dyc[i];
    }
    const double al = fmin(0.999 * bred(tt, NZV, 1, SC, tid), 1.0);
    if (tid < NZV) {
      x[tid] += al * dxa[tid];
      s[tid] += al * dsa[tid];
      z[tid] += al * dza[tid];
    } else if (tid >= 128 && tid < 153) {
      const int i = tid - 128;
      yv[i] += al * dya[i];
    }
  }
  __syncthreads();
  if (tid < NZV) xout[(size_t)b * NZV + tid] = (float)bx[tid];
}

// =====================================================================
// Kernel 3: transformed/normalized query features, compat dots, output.
// =====================================================================
__global__ void __launch_bounds__(TPB) out_kernel(
    const float* __restrict__ test, const float* __restrict__ train,
    const int* __restrict__ usimple, const float* __restrict__ xin,
    float* __restrict__ out) {
  const int b = blockIdx.x;
  const int tid = threadIdx.x;
  const int lane = tid & 63;
  const int w = tid >> 6;
  const bool us = (usimple[0] != 0);

  __shared__ float qtile[15 * DF];
  __shared__ float dots[15 * 26];
  __shared__ float xls[NZV];

  if (tid < NZV) xls[tid] = xin[(size_t)b * NZV + tid];

  const float* tb = train + (size_t)b * NSUP * DF;
  float fr[5][10];
#pragma unroll
  for (int j = 0; j < 5; ++j) {
    const int r = 5 * w + j;
    float ss = 0.0f;
#pragma unroll
    for (int c = 0; c < 10; ++c) {
      float v = tb[r * DF + lane + 64 * c];
      if (us) v = simple_tf(v);
      fr[j][c] = v;
      ss += v * v;
    }
#pragma unroll
    for (int off = 32; off > 0; off >>= 1) ss += __shfl_xor(ss, off);
    const float sc = 1.0f / fmaxf(sqrtf(ss), 1e-12f);
#pragma unroll
    for (int c = 0; c < 10; ++c) fr[j][c] *= sc;
  }

  const float* qb = test + (size_t)b * NQ * DF;
  for (int t = 0; t < 5; ++t) {
#pragma unroll
    for (int jj = 0; jj < 3; ++jj) {
      const int ql = 3 * w + jj;
      const float* qr = qb + (size_t)(t * 15 + ql) * DF;
      float qv[10];
      float ss = 0.0f;
#pragma unroll
      for (int c = 0; c < 10; ++c) {
        float v = qr[lane + 64 * c];
        if (us) v = simple_tf(v);
        qv[c] = v;
        ss += v * v;
      }
#pragma unroll
      for (int off = 32; off > 0; off >>= 1) ss += __shfl_xor(ss, off);
      const float sc = 1.0f / fmaxf(sqrtf(ss), 1e-12f);
#pragma unroll
      for (int c = 0; c < 10; ++c)
        qtile[ql * DF + lane + 64 * c] = qv[c] * sc;
    }
    __syncthreads();
    for (int ql = 0; ql < 15; ++ql) {
      float p0 = 0.f, p1 = 0.f, p2 = 0.f, p3 = 0.f, p4 = 0.f;
#pragma unroll
      for (int c = 0; c < 10; ++c) {
        const float qv = qtile[ql * DF + lane + 64 * c];
        p0 += fr[0][c] * qv;
        p1 += fr[1][c] * qv;
        p2 += fr[2][c] * qv;
        p3 += fr[3][c] * qv;
        p4 += fr[4][c] * qv;
      }
#pragma unroll
      for (int off = 32; off > 0; off >>= 1) {
        p0 += __shfl_xor(p0, off);
        p1 += __shfl_xor(p1, off);
        p2 += __shfl_xor(p2, off);
        p3 += __shfl_xor(p3, off);
        p4 += __shfl_xor(p4, off);
      }
      if (lane == 0) {
        dots[ql * 26 + 5 * w + 0] = p0;
        dots[ql * 26 + 5 * w + 1] = p1;
        dots[ql * 26 + 5 * w + 2] = p2;
        dots[ql * 26 + 5 * w + 3] = p3;
        dots[ql * 26 + 5 * w + 4] = p4;
      }
    }
    __syncthreads();
    if (tid < 75) {
      const int ql = tid / 5, w2 = tid - 5 * (tid / 5);
      float acc = 0.0f;
#pragma unroll
      for (int s = 0; s < NSUP; ++s)
        acc += xls[s * 5 + w2] * dots[ql * 26 + s];
      out[((size_t)b * NQ + t * 15 + ql) * 5 + w2] = acc;
    }
    __syncthreads();
  }
}

// =====================================================================
extern "C" void kernel_launch(void* const* d_in, const int* in_sizes, int n_in,
                              void* d_out, int out_size, void* d_ws,
                              size_t ws_size, hipStream_t stream) {
  const float* ftest = (const float*)d_in[0];
  const float* ftrain = (const float*)d_in[1];
  const int* usimple = (const int*)d_in[4];
  float* out = (float*)d_out;
  const int B = in_sizes[1] / (NSUP * DF);

  double* Mg = (double*)d_ws;                               // B * 650 doubles
  float* xws = (float*)((char*)d_ws + (size_t)B * 650 * sizeof(double));

  feat_kernel<<<dim3(B), dim3(TPB), 0, stream>>>(ftrain, usimple, Mg);
  qp_kernel<<<dim3(B), dim3(TPB), 0, stream>>>(Mg, xws);
  out_kernel<<<dim3(B), dim3(TPB), 0, stream>>>(ftest, ftrain, usimple, xws, out);
}

// Round 4
// 680.407 us; speedup vs baseline: 3.0259x; 3.0259x over previous
//
#include <hip/hip_runtime.h>
#include <math.h>

#define NWAY 5
#define NSUP 25
#define NZV  125
#define DF   640
#define NQ   75
#define TPB  320

// ---------------- shared-memory offsets for qp_kernel (in doubles) ----------
#define OFF_HINV 0      // 5 * 25*26 = 3250
#define OFF_WINV 3250   // 650
#define OFF_X    3900
#define OFF_S    4028
#define OFF_Z    4156
#define OFF_BX   4284
#define OFF_RX   4412
#define OFF_RZ   4540
#define OFF_TT   4668
#define OFF_C1   4796
#define OFF_DD   4924
#define OFF_VV   5052
#define OFF_DXA  5180
#define OFF_DSA  5308
#define OFF_DZA  5436
#define OFF_RSC  5564
#define OFF_DXC  5692
#define OFF_DSC  5820
#define OFF_DZC  5948
#define OFF_YV   6076   // 32 each from here
#define OFF_RY   6108
#define OFF_C2   6140
#define OFF_GG   6172
#define OFF_DYA  6204
#define OFF_DYC  6236
#define OFF_Z125 6268   // 128 zeros
#define OFF_Z25  6396   // 32 zeros
#define OFF_SC   6428   // scalars: [0]=best_res [1]=better flag [15]=reduce slot
#define SH_TOT   6448

__device__ __forceinline__ float simple_tf(float x) {
  float tp = fmaxf(x, 0.0f) + 1e-5f;
  float tn = fmaxf(-x, 0.0f) + 1e-5f;
  float lp = __logf(1.0f / tp + 1.0f);
  float ln_ = __logf(1.0f / tn + 1.0f);
  float pos = __expf(-1.3f * __logf(lp));
  float neg = __expf(-1.3f * __logf(ln_));
  return pos - neg;
}

// =====================================================================
// Kernel 1: transform + l2norm train features, Gram K, M = K + I (fp64)
// =====================================================================
__global__ void __launch_bounds__(TPB, 2) feat_kernel(
    const float* __restrict__ train, const int* __restrict__ usimple,
    double* __restrict__ Mg) {
  const int b = blockIdx.x;
  const int tid = threadIdx.x;
  const int lane = tid & 63;
  const int w = tid >> 6;
  __shared__ __align__(16) float ftn[NSUP * 644];   // padded stride 644
  const bool us = (usimple[0] != 0);
  const float* tb = train + (size_t)b * NSUP * DF;

  for (int idx = tid; idx < NSUP * DF; idx += TPB) {
    float v = tb[idx];
    if (us) v = simple_tf(v);
    int r = idx / DF, c = idx - r * DF;
    ftn[r * 644 + c] = v;
  }
  __syncthreads();
#pragma unroll
  for (int jj = 0; jj < 5; ++jj) {
    const int r = w + 5 * jj;
    float acc = 0.0f;
#pragma unroll
    for (int c = 0; c < 10; ++c) {
      float t = ftn[r * 644 + lane + 64 * c];
      acc += t * t;
    }
#pragma unroll
    for (int off = 32; off > 0; off >>= 1) acc += __shfl_xor(acc, off);
    const float sc = 1.0f / fmaxf(sqrtf(acc), 1e-12f);
#pragma unroll
    for (int c = 0; c < 10; ++c) ftn[r * 644 + lane + 64 * c] *= sc;
  }
  __syncthreads();
  double* Mb = Mg + (size_t)b * 650;
  for (int pi = tid; pi < 325; pi += TPB) {
    int i = 0, rem = pi;
    while (rem >= NSUP - i) { rem -= NSUP - i; ++i; }
    const int j = i + rem;
    const float4* ra = (const float4*)(ftn + i * 644);
    const float4* rb = (const float4*)(ftn + j * 644);
    double acc = 0.0;
    for (int c = 0; c < 160; ++c) {
      float4 av = ra[c], bv = rb[c];
      acc += (double)av.x * bv.x + (double)av.y * bv.y +
             (double)av.z * bv.z + (double)av.w * bv.w;
    }
    if (i == j) acc += 1.0;
    Mb[i * 26 + j] = acc;
    if (i != j) Mb[j * 26 + i] = acc;
  }
}

// =====================================================================
// In-place Gauss-Jordan inversion of a 25x25 SPD matrix.
// Layout: lane = COLUMN c (lanes 0..24); a[r] = A[r][c].
// Only ONE 25-double array lives in registers (50 VGPRs) + 1-2 temps;
// the Cholesky+triangular-solve version needed a[25]+col[25] (100 VGPRs
// fully live) which the allocator spilled to scratch in R1-R3 (the
// 2 GB/dispatch private-memory traffic = the whole 1.6 ms runtime).
// Per pivot the column-j factor f is shfl'd one row at a time and
// consumed immediately, so the live set stays ~80 VGPRs total.
// No pivoting: SPD in fp64, kappa <~ 1e4 -> stable (LDL^T-class).
// =====================================================================
template <int J>
__device__ __forceinline__ void gj_pivot(double (&a)[25], const int lane) {
  const double djj = __shfl(a[J], J);
  const double pinv = 1.0 / djj;
  a[J] = ((lane == J) ? 1.0 : a[J]) * pinv;   // scale row J (lane J -> pinv)
#pragma unroll
  for (int r = 0; r < 25; ++r) {
    if (r != J) {
      const double f = __shfl(a[r], J);       // A[r][J] before update
      a[r] = ((lane == J) ? 0.0 : a[r]) - f * a[J];
    }
  }
}
template <int J>
__device__ __forceinline__ void gj_all(double (&a)[25], const int lane) {
  if constexpr (J < 25) {
    gj_pivot<J>(a, lane);
    gj_all<J + 1>(a, lane);
  }
}
__device__ __forceinline__ void gjinv25(double (&a)[25], const int lane) {
  gj_all<0>(a, lane);   // a[] now holds column `lane` of A^{-1}
}

__device__ __forceinline__ void factorize(const double* Msh, double* SH,
                                          const int tid) {
  const int lane = tid & 63;
  const int w = tid >> 6;
  const double* dd = SH + OFF_DD;
  double* Hinv = SH + OFF_HINV;
  double* Winv = SH + OFF_WINV;
  {
    double a[25];
#pragma unroll
    for (int j = 0; j < 25; ++j) a[j] = 0.0;
    if (lane < 25) {
      // lane = column; M symmetric so row-read works for column load
#pragma unroll
      for (int j = 0; j < 25; ++j)
        a[j] = Msh[lane * 26 + j] + ((j == lane) ? dd[lane * 5 + w] : 0.0);
    }
    gjinv25(a, lane);
    if (lane < 25) {
#pragma unroll
      for (int i = 0; i < 25; ++i) Hinv[w * 650 + i * 26 + lane] = a[i];
    }
  }
  __syncthreads();
  for (int idx = tid; idx < 625; idx += TPB) {
    const int i = idx / 25, r = idx - i * 25;
    double acc = 0.0;
#pragma unroll
    for (int k = 0; k < 5; ++k) acc += Hinv[k * 650 + i * 26 + r];
    Winv[i * 26 + r] = acc;
  }
  __syncthreads();
  if (w == 0) {
    double a[25];
#pragma unroll
    for (int j = 0; j < 25; ++j) a[j] = 0.0;
    if (lane < 25) {
#pragma unroll
      for (int j = 0; j < 25; ++j) a[j] = Winv[lane * 26 + j];
    }
    gjinv25(a, lane);
    if (lane < 25) {
#pragma unroll
      for (int i = 0; i < 25; ++i) Winv[i * 26 + lane] = a[i];
    }
  }
  __syncthreads();
}

__device__ __forceinline__ void kkt_solve(
    const double* Msh, double* SH, const double* rx, const double* rs,
    const double* rz, const double* ry, double* dx, double* ds, double* dz,
    double* dy, const int tid) {
  const int lane = tid & 63;
  const int w = tid >> 6;
  const double* dd = SH + OFF_DD;
  const double* Hinv = SH + OFF_HINV;
  const double* Winv = SH + OFF_WINV;
  double* tt = SH + OFF_TT;
  double* c1 = SH + OFF_C1;
  double* c2 = SH + OFF_C2;
  double* vv = SH + OFF_VV;
  double* gg = SH + OFF_GG;

  if (tid < NZV) tt[tid] = rz[tid] - rs[tid] / dd[tid];
  __syncthreads();
  if (tid < NZV) {
    const int i = tid / 5, k = tid - i * 5;
    double acc = -rx[tid];
#pragma unroll
    for (int j = 0; j < 25; ++j) acc += Msh[i * 26 + j] * tt[j * 5 + k];
    c1[tid] = acc;
  } else if (tid >= 128 && tid < 153) {
    const int i = tid - 128;
    double acc = -ry[i];
#pragma unroll
    for (int k = 0; k < 5; ++k) acc += tt[i * 5 + k];
    c2[i] = acc;
  }
  __syncthreads();
  if (lane < 25) {
    double acc = 0.0;
#pragma unroll
    for (int j = 0; j < 25; ++j)
      acc += Hinv[w * 650 + lane * 26 + j] * c1[j * 5 + w];
    vv[lane * 5 + w] = acc;
  }
  __syncthreads();
  if (tid < 25) {
    double acc = -c2[tid];
#pragma unroll
    for (int k = 0; k < 5; ++k) acc += vv[tid * 5 + k];
    gg[tid] = acc;
  }
  __syncthreads();
  if (tid < 25) {
    double acc = 0.0;
#pragma unroll
    for (int r = 0; r < 25; ++r) acc += Winv[tid * 26 + r] * gg[r];
    dy[tid] = acc;
  }
  __syncthreads();
  if (lane < 25) {
    double acc = 0.0;
#pragma unroll
    for (int j = 0; j < 25; ++j) acc += Hinv[w * 650 + lane * 26 + j] * dy[j];
    const int v = lane * 5 + w;
    const double u = vv[v] - acc;
    const double dzv = dd[v] * u;
    dz[v] = dzv;
    dx[v] = u - tt[v];
    ds[v] = (-rs[v] - dzv) / dd[v];
  }
  __syncthreads();
}

__device__ __forceinline__ double bred(const double* buf, int n, int ismin,
                                       double* SC, const int tid) {
  __syncthreads();
  if (tid < 64) {
    double acc = ismin ? 1e300 : 0.0;
    for (int m = tid; m < n; m += 64) {
      const double v = buf[m];
      acc = ismin ? fmin(acc, v) : (acc + v);
    }
#pragma unroll
    for (int off = 32; off > 0; off >>= 1) {
      const double o = __shfl_xor(acc, off);
      acc = ismin ? fmin(acc, o) : (acc + o);
    }
    if (tid == 0) SC[15] = acc;
  }
  __syncthreads();
  return SC[15];
}

__global__ void __launch_bounds__(TPB, 2) qp_kernel(
    const double* __restrict__ Mg, float* __restrict__ xout) {
  const int b = blockIdx.x;
  const int tid = threadIdx.x;
  __shared__ double SH[SH_TOT];
  __shared__ double Msh[NSUP * 26];

  double* x = SH + OFF_X;
  double* s = SH + OFF_S;
  double* z = SH + OFF_Z;
  double* bx = SH + OFF_BX;
  double* rx = SH + OFF_RX;
  double* rz = SH + OFF_RZ;
  double* tt = SH + OFF_TT;
  double* dd = SH + OFF_DD;
  double* dxa = SH + OFF_DXA;
  double* dsa = SH + OFF_DSA;
  double* dza = SH + OFF_DZA;
  double* rsc = SH + OFF_RSC;
  double* dxc = SH + OFF_DXC;
  double* dsc = SH + OFF_DSC;
  double* dzc = SH + OFF_DZC;
  double* yv = SH + OFF_YV;
  double* ry = SH + OFF_RY;
  double* dya = SH + OFF_DYA;
  double* dyc = SH + OFF_DYC;
  double* z125 = SH + OFF_Z125;
  double* z25 = SH + OFF_Z25;
  double* SC = SH + OFF_SC;

  for (int idx = tid; idx < NSUP * 26; idx += TPB)
    Msh[idx] = Mg[(size_t)b * 650 + idx];

  if (tid < NZV) {
    const int i = tid / 5, k = tid - i * 5;
    const double oh = (k == (i % 5)) ? 1.0 : 0.0;
    rx[tid] = -oh;
    rz[tid] = -0.1 * oh;
    dd[tid] = 1.0;
    rsc[tid] = 0.0;
    z125[tid] = 0.0;
  } else if (tid >= 128 && tid < 153) {
    const int i = tid - 128;
    ry[i] = 0.0;
    z25[i] = 0.0;
  }
  if (tid == 0) SC[0] = 1e300;
  __syncthreads();

  factorize(Msh, SH, tid);
  kkt_solve(Msh, SH, rx, rsc, rz, ry, x, s, z, yv, tid);

  {
    const double ms = bred(s, NZV, 1, SC, tid);
    if (ms < 0.0 && tid < NZV) s[tid] -= (ms - 1.0);
    const double mz = bred(z, NZV, 1, SC, tid);
    if (mz < 0.0 && tid < NZV) z[tid] -= (mz - 1.0);
  }
  if (tid < NZV) bx[tid] = x[tid];

#pragma unroll 1
  for (int it = 0; it < 3; ++it) {
    __syncthreads();
    if (tid < NZV) {
      const int i = tid / 5, k = tid - i * 5;
      double acc = 0.0;
#pragma unroll
      for (int j = 0; j < 25; ++j) acc += Msh[i * 26 + j] * x[j * 5 + k];
      const double oh = (k == (i % 5)) ? 1.0 : 0.0;
      rx[tid] = yv[i] + z[tid] + acc - oh;
      rz[tid] = x[tid] + s[tid] - 0.1 * oh;
      tt[tid] = s[tid] * z[tid];
    } else if (tid >= 128 && tid < 153) {
      const int i = tid - 128;
      double acc = 0.0;
#pragma unroll
      for (int k = 0; k < 5; ++k) acc += x[i * 5 + k];
      ry[i] = acc;
    }
    const double szsum = bred(tt, NZV, 0, SC, tid);
    if (tid < NZV) tt[tid] = rx[tid] * rx[tid];
    const double snx = bred(tt, NZV, 0, SC, tid);
    if (tid < NZV) tt[tid] = rz[tid] * rz[tid];
    const double snz = bred(tt, NZV, 0, SC, tid);
    if (tid < 25) tt[tid] = ry[tid] * ry[tid];
    const double sny = bred(tt, 25, 0, SC, tid);
    const double mu = fabs(szsum) / 125.0;
    const double res = sqrt(snz + 1e-30) + sqrt(sny + 1e-30) +
                       sqrt(snx + 1e-30) + 125.0 * mu;
    if (tid == 0) {
      if (res < SC[0]) { SC[0] = res; SC[1] = 1.0; } else SC[1] = 0.0;
    }
    __syncthreads();
    if (SC[1] != 0.0 && tid < NZV) bx[tid] = x[tid];
    if (it == 2) break;
    __syncthreads();

    if (tid < NZV) dd[tid] = z[tid] / s[tid];
    __syncthreads();
    factorize(Msh, SH, tid);
    kkt_solve(Msh, SH, rx, z, rz, ry, dxa, dsa, dza, dya, tid);
    if (tid < NZV) {
      const double a1 = (dza[tid] < 0.0) ? (-z[tid] / dza[tid]) : 1e12;
      const double a2 = (dsa[tid] < 0.0) ? (-s[tid] / dsa[tid]) : 1e12;
      tt[tid] = fmin(a1, a2);
    }
    const double aff = fmin(bred(tt, NZV, 1, SC, tid), 1.0);
    if (tid < NZV)
      tt[tid] = (s[tid] + aff * dsa[tid]) * (z[tid] + aff * dza[tid]);
    const double num = bred(tt, NZV, 0, SC, tid);
    const double sg = num / szsum;
    const double musig = mu * (sg * sg * sg);
    if (tid < NZV) rsc[tid] = (-musig + dsa[tid] * dza[tid]) / s[tid];
    __syncthreads();
    kkt_solve(Msh, SH, z125, rsc, z125, z25, dxc, dsc, dzc, dyc, tid);
    if (tid < NZV) {
      const double ddx = dxa[tid] + dxc[tid];
      const double dds = dsa[tid] + dsc[tid];
      const double ddz = dza[tid] + dzc[tid];
      dxa[tid] = ddx; dsa[tid] = dds; dza[tid] = ddz;
      const double a1 = (ddz < 0.0) ? (-z[tid] / ddz) : 1e12;
      const double a2 = (dds < 0.0) ? (-s[tid] / dds) : 1e12;
      tt[tid] = fmin(a1, a2);
    } else if (tid >= 128 && tid < 153) {
      const int i = tid - 128;
      dya[i] += dyc[i];
    }
    const double al = fmin(0.999 * bred(tt, NZV, 1, SC, tid), 1.0);
    if (tid < NZV) {
      x[tid] += al * dxa[tid];
      s[tid] += al * dsa[tid];
      z[tid] += al * dza[tid];
    } else if (tid >= 128 && tid < 153) {
      const int i = tid - 128;
      yv[i] += al * dya[i];
    }
  }
  __syncthreads();
  if (tid < NZV) xout[(size_t)b * NZV + tid] = (float)bx[tid];
}

// =====================================================================
// Kernel 3: transformed/normalized query features, compat dots, output.
// =====================================================================
__global__ void __launch_bounds__(TPB) out_kernel(
    const float* __restrict__ test, const float* __restrict__ train,
    const int* __restrict__ usimple, const float* __restrict__ xin,
    float* __restrict__ out) {
  const int b = blockIdx.x;
  const int tid = threadIdx.x;
  const int lane = tid & 63;
  const int w = tid >> 6;
  const bool us = (usimple[0] != 0);

  __shared__ float qtile[15 * DF];
  __shared__ float dots[15 * 26];
  __shared__ float xls[NZV];

  if (tid < NZV) xls[tid] = xin[(size_t)b * NZV + tid];

  const float* tb = train + (size_t)b * NSUP * DF;
  float fr[5][10];
#pragma unroll
  for (int j = 0; j < 5; ++j) {
    const int r = 5 * w + j;
    float ss = 0.0f;
#pragma unroll
    for (int c = 0; c < 10; ++c) {
      float v = tb[r * DF + lane + 64 * c];
      if (us) v = simple_tf(v);
      fr[j][c] = v;
      ss += v * v;
    }
#pragma unroll
    for (int off = 32; off > 0; off >>= 1) ss += __shfl_xor(ss, off);
    const float sc = 1.0f / fmaxf(sqrtf(ss), 1e-12f);
#pragma unroll
    for (int c = 0; c < 10; ++c) fr[j][c] *= sc;
  }

  const float* qb = test + (size_t)b * NQ * DF;
  for (int t = 0; t < 5; ++t) {
#pragma unroll
    for (int jj = 0; jj < 3; ++jj) {
      const int ql = 3 * w + jj;
      const float* qr = qb + (size_t)(t * 15 + ql) * DF;
      float qv[10];
      float ss = 0.0f;
#pragma unroll
      for (int c = 0; c < 10; ++c) {
        float v = qr[lane + 64 * c];
        if (us) v = simple_tf(v);
        qv[c] = v;
        ss += v * v;
      }
#pragma unroll
      for (int off = 32; off > 0; off >>= 1) ss += __shfl_xor(ss, off);
      const float sc = 1.0f / fmaxf(sqrtf(ss), 1e-12f);
#pragma unroll
      for (int c = 0; c < 10; ++c)
        qtile[ql * DF + lane + 64 * c] = qv[c] * sc;
    }
    __syncthreads();
    for (int ql = 0; ql < 15; ++ql) {
      float p0 = 0.f, p1 = 0.f, p2 = 0.f, p3 = 0.f, p4 = 0.f;
#pragma unroll
      for (int c = 0; c < 10; ++c) {
        const float qv = qtile[ql * DF + lane + 64 * c];
        p0 += fr[0][c] * qv;
        p1 += fr[1][c] * qv;
        p2 += fr[2][c] * qv;
        p3 += fr[3][c] * qv;
        p4 += fr[4][c] * qv;
      }
#pragma unroll
      for (int off = 32; off > 0; off >>= 1) {
        p0 += __shfl_xor(p0, off);
        p1 += __shfl_xor(p1, off);
        p2 += __shfl_xor(p2, off);
        p3 += __shfl_xor(p3, off);
        p4 += __shfl_xor(p4, off);
      }
      if (lane == 0) {
        dots[ql * 26 + 5 * w + 0] = p0;
        dots[ql * 26 + 5 * w + 1] = p1;
        dots[ql * 26 + 5 * w + 2] = p2;
        dots[ql * 26 + 5 * w + 3] = p3;
        dots[ql * 26 + 5 * w + 4] = p4;
      }
    }
    __syncthreads();
    if (tid < 75) {
      const int ql = tid / 5, w2 = tid - 5 * (tid / 5);
      float acc = 0.0f;
#pragma unroll
      for (int s = 0; s < NSUP; ++s)
        acc += xls[s * 5 + w2] * dots[ql * 26 + s];
      out[((size_t)b * NQ + t * 15 + ql) * 5 + w2] = acc;
    }
    __syncthreads();
  }
}

// =====================================================================
extern "C" void kernel_launch(void* const* d_in, const int* in_sizes, int n_in,
                              void* d_out, int out_size, void* d_ws,
                              size_t ws_size, hipStream_t stream) {
  const float* ftest = (const float*)d_in[0];
  const float* ftrain = (const float*)d_in[1];
  const int* usimple = (const int*)d_in[4];
  float* out = (float*)d_out;
  const int B = in_sizes[1] / (NSUP * DF);

  double* Mg = (double*)d_ws;                               // B * 650 doubles
  float* xws = (float*)((char*)d_ws + (size_t)B * 650 * sizeof(double));

  feat_kernel<<<dim3(B), dim3(TPB), 0, stream>>>(ftrain, usimple, Mg);
  qp_kernel<<<dim3(B), dim3(TPB), 0, stream>>>(Mg, xws);
  out_kernel<<<dim3(B), dim3(TPB), 0, stream>>>(ftest, ftrain, usimple, xws, out);
}